// Round 1
// baseline (762.181 us; speedup 1.0000x reference)
//
#include <hip/hip_runtime.h>

#define C_CH 128
#define G_SEGS 1024

// One half-wave (32 lanes) owns one row at a time; lane loads float4 -> 32*16B
// covers the whole 512B row coalesced. Chunked contiguous row ranges so the
// sorted `batch` gives long same-segment runs => register accumulation with
// rare atomic flushes.
__global__ __launch_bounds__(256) void nap_main(
    const float* __restrict__ x, const float* __restrict__ W,
    const float* __restrict__ b, const int* __restrict__ batch,
    float* __restrict__ U, float* __restrict__ Z,
    float* __restrict__ e_out, int N)
{
    const int tid = blockIdx.x * blockDim.x + threadIdx.x;
    const int hw  = tid >> 5;                      // global half-wave id
    const int sub = threadIdx.x & 31;              // lane within half-wave
    const int nhw = (gridDim.x * blockDim.x) >> 5;
    const int chunk = (N + nhw - 1) / nhw;
    const int row0 = hw * chunk;
    const int row1 = min(N, row0 + chunk);

    const float4 w4 = ((const float4*)W)[sub];
    const float bv = b[0];

    float4 acc = make_float4(0.f, 0.f, 0.f, 0.f);
    int cur = -1;
    float zloc = 0.f;

    for (int row = row0; row < row1; ++row) {
        const float4 xv = ((const float4*)(x + (size_t)row * C_CH))[sub];
        float d = xv.x * w4.x + xv.y * w4.y + xv.z * w4.z + xv.w * w4.w;
        // butterfly sum across the 32-lane half-wave (xor<=16 stays in-half)
        d += __shfl_xor(d, 1);
        d += __shfl_xor(d, 2);
        d += __shfl_xor(d, 4);
        d += __shfl_xor(d, 8);
        d += __shfl_xor(d, 16);
        const float e = __expf(d + bv);
        const int seg = batch[row];
        if (seg != cur) {
            if (cur >= 0) {
                float* dst = U + (size_t)cur * C_CH + sub * 4;
                atomicAdd(dst + 0, acc.x);
                atomicAdd(dst + 1, acc.y);
                atomicAdd(dst + 2, acc.z);
                atomicAdd(dst + 3, acc.w);
            }
            cur = seg;
            acc = make_float4(0.f, 0.f, 0.f, 0.f);
        }
        acc.x += e * xv.x;
        acc.y += e * xv.y;
        acc.z += e * xv.z;
        acc.w += e * xv.w;
        if (sub == 0) {
            zloc += e;
            e_out[row] = e;   // unnormalized exp into alpha slot of d_out
        }
    }
    if (cur >= 0) {
        float* dst = U + (size_t)cur * C_CH + sub * 4;
        atomicAdd(dst + 0, acc.x);
        atomicAdd(dst + 1, acc.y);
        atomicAdd(dst + 2, acc.z);
        atomicAdd(dst + 3, acc.w);
    }
    if (sub == 0 && row0 < row1) atomicAdd(Z, zloc);
}

__global__ __launch_bounds__(256) void nap_finalize(
    const float* __restrict__ U, const float* __restrict__ Z,
    float* __restrict__ pooled, float* __restrict__ alpha,
    int gc, int n)
{
    const float inv = 1.0f / (*Z);
    const int tid = blockIdx.x * blockDim.x + threadIdx.x;
    const int stride = gridDim.x * blockDim.x;
    const int gc4 = gc >> 2;
    const int n4 = n >> 2;
    for (int k = tid; k < gc4; k += stride) {
        float4 u = ((const float4*)U)[k];
        u.x *= inv; u.y *= inv; u.z *= inv; u.w *= inv;
        ((float4*)pooled)[k] = u;
    }
    for (int k = tid; k < n4; k += stride) {
        float4 e = ((const float4*)alpha)[k];
        e.x *= inv; e.y *= inv; e.z *= inv; e.w *= inv;
        ((float4*)alpha)[k] = e;
    }
    // scalar tails (N, G*C are multiples of 4 here, but stay general)
    for (int k = gc4 * 4 + tid; k < gc; k += stride) pooled[k] = U[k] * inv;
    for (int k = n4 * 4 + tid; k < n; k += stride) alpha[k] = alpha[k] * inv;
}

extern "C" void kernel_launch(void* const* d_in, const int* in_sizes, int n_in,
                              void* d_out, int out_size, void* d_ws, size_t ws_size,
                              hipStream_t stream) {
    const float* x     = (const float*)d_in[0];
    const float* W     = (const float*)d_in[1];
    const float* b     = (const float*)d_in[2];
    const int*   batch = (const int*)d_in[3];
    const int N = in_sizes[3];

    float* U = (float*)d_ws;                 // [G_SEGS * C_CH] unnormalized sums
    float* Z = U + (size_t)G_SEGS * C_CH;    // [1] global sum of exp
    float* pooled = (float*)d_out;                      // [G_SEGS * C_CH]
    float* alpha  = pooled + (size_t)G_SEGS * C_CH;     // [N]

    // ws is poisoned 0xAA before every timed launch -> zero U and Z
    hipMemsetAsync(d_ws, 0, ((size_t)G_SEGS * C_CH + 1) * sizeof(float), stream);

    nap_main<<<2048, 256, 0, stream>>>(x, W, b, batch, U, Z, alpha, N);
    nap_finalize<<<512, 256, 0, stream>>>(U, Z, pooled, alpha, G_SEGS * C_CH, N);
}

// Round 2
// 675.147 us; speedup vs baseline: 1.1289x; 1.1289x over previous
//
#include <hip/hip_runtime.h>

#define C_CH 128
#define G_SEGS 1024

// Flush a lane's per-segment float4 accumulator into U[seg][col4*4..+3].
__device__ __forceinline__ void flush_acc(float* __restrict__ U, int seg, int col4,
                                          float4& acc) {
    float* dst = U + (size_t)seg * C_CH + col4 * 4;
    atomicAdd(dst + 0, acc.x);
    atomicAdd(dst + 1, acc.y);
    atomicAdd(dst + 2, acc.z);
    atomicAdd(dst + 3, acc.w);
    acc = make_float4(0.f, 0.f, 0.f, 0.f);
}

// 8 rows per wave iteration:
//   float4 index f = i*64 + lane  (i=0..3)  ->  row = rb + 2i + (lane>>5),
//   col4 = lane&31. Each of the 4 loads is a fully contiguous 1KB wave load.
//   Dot partials reduce with a 5-level butterfly confined to each 32-lane half
//   (4 independent chains interleaved). Segment logic fast-paths on the
//   wave-uniform check batch[rb]==batch[rb+7] (sorted batch, ~977-row runs).
__global__ __launch_bounds__(256) void nap_main(
    const float* __restrict__ x, const float* __restrict__ W,
    const float* __restrict__ b, const int* __restrict__ batch,
    float* __restrict__ U, float* __restrict__ Z,
    float* __restrict__ e_out, int N)
{
    __shared__ float zred[4];
    const int lane = threadIdx.x & 63;
    const int wid  = threadIdx.x >> 6;
    const int wave = (blockIdx.x * blockDim.x + threadIdx.x) >> 6;
    const int nwaves = (gridDim.x * blockDim.x) >> 6;
    int chunk = (N + nwaves - 1) / nwaves;
    chunk = (chunk + 7) & ~7;                 // multiple of 8 rows per wave
    const int row0 = wave * chunk;
    const int row1 = min(N, row0 + chunk);

    const int col4 = lane & 31;               // which float4 of a row this lane owns
    const int h    = lane >> 5;               // row-parity half
    const float4 w4 = ((const float4*)W)[col4];
    const float bv = b[0];
    const float4* x4 = (const float4*)x;

    float4 acc = make_float4(0.f, 0.f, 0.f, 0.f);
    float zloc = 0.f;
    int cur = -1;

    int rb = row0;
    for (; rb + 8 <= row1; rb += 8) {
        const float4* p = x4 + (size_t)rb * (C_CH / 4);
        float4 a0 = p[lane];                  // rows rb+0, rb+1
        float4 a1 = p[64  + lane];            // rows rb+2, rb+3
        float4 a2 = p[128 + lane];            // rows rb+4, rb+5
        float4 a3 = p[192 + lane];            // rows rb+6, rb+7
        const int bfirst = batch[rb];         // wave-uniform -> s_load
        const int blast  = batch[rb + 7];

        float d0 = a0.x * w4.x + a0.y * w4.y + a0.z * w4.z + a0.w * w4.w;
        float d1 = a1.x * w4.x + a1.y * w4.y + a1.z * w4.z + a1.w * w4.w;
        float d2 = a2.x * w4.x + a2.y * w4.y + a2.z * w4.z + a2.w * w4.w;
        float d3 = a3.x * w4.x + a3.y * w4.y + a3.z * w4.z + a3.w * w4.w;
        #pragma unroll
        for (int m = 1; m <= 16; m <<= 1) {   // 4 chains interleaved, halves only
            d0 += __shfl_xor(d0, m);
            d1 += __shfl_xor(d1, m);
            d2 += __shfl_xor(d2, m);
            d3 += __shfl_xor(d3, m);
        }
        const float e0 = __expf(d0 + bv);
        const float e1 = __expf(d1 + bv);
        const float e2 = __expf(d2 + bv);
        const float e3 = __expf(d3 + bv);

        if (bfirst == blast) {                // uniform fast path: one segment
            if (bfirst != cur) {
                if (cur >= 0) flush_acc(U, cur, col4, acc);
                cur = bfirst;
            }
            acc.x += e0 * a0.x + e1 * a1.x + e2 * a2.x + e3 * a3.x;
            acc.y += e0 * a0.y + e1 * a1.y + e2 * a2.y + e3 * a3.y;
            acc.z += e0 * a0.z + e1 * a1.z + e2 * a2.z + e3 * a3.z;
            acc.w += e0 * a0.w + e1 * a1.w + e2 * a2.w + e3 * a3.w;
        } else {                              // rare: boundary inside the group
            const int r  = rb + h;            // this half's rows: r, r+2, r+4, r+6
            const int s0 = batch[r];
            const int s1 = batch[r + 2];
            const int s2 = batch[r + 4];
            const int s3 = batch[r + 6];
            if (s0 != cur) { if (cur >= 0) flush_acc(U, cur, col4, acc); cur = s0; }
            acc.x += e0 * a0.x; acc.y += e0 * a0.y; acc.z += e0 * a0.z; acc.w += e0 * a0.w;
            if (s1 != cur) { flush_acc(U, cur, col4, acc); cur = s1; }
            acc.x += e1 * a1.x; acc.y += e1 * a1.y; acc.z += e1 * a1.z; acc.w += e1 * a1.w;
            if (s2 != cur) { flush_acc(U, cur, col4, acc); cur = s2; }
            acc.x += e2 * a2.x; acc.y += e2 * a2.y; acc.z += e2 * a2.z; acc.w += e2 * a2.w;
            if (s3 != cur) { flush_acc(U, cur, col4, acc); cur = s3; }
            acc.x += e3 * a3.x; acc.y += e3 * a3.y; acc.z += e3 * a3.z; acc.w += e3 * a3.w;
        }

        // alpha (unnormalized exp) store: pack 8 rows into two float4 stores
        const float p0 = __shfl_xor(e0, 32);
        const float p1 = __shfl_xor(e1, 32);
        const float p2 = __shfl_xor(e2, 32);
        const float p3 = __shfl_xor(e3, 32);
        if (lane == 0) {
            ((float4*)(e_out + rb))[0] = make_float4(e0, p0, e1, p1);
            zloc += e0 + e1 + e2 + e3;
        } else if (lane == 32) {
            ((float4*)(e_out + rb))[1] = make_float4(p2, e2, p3, e3);
            zloc += e0 + e1 + e2 + e3;
        }
    }

    // generic scalar tail (never runs for N % 8 == 0, kept for safety)
    for (; rb < row1; ++rb) {
        const float4 xv = x4[(size_t)rb * (C_CH / 4) + col4];
        float d = xv.x * w4.x + xv.y * w4.y + xv.z * w4.z + xv.w * w4.w;
        #pragma unroll
        for (int m = 1; m <= 16; m <<= 1) d += __shfl_xor(d, m);
        const float e = __expf(d + bv);
        const int s = batch[rb];
        if (h == 0) {
            if (s != cur) { if (cur >= 0) flush_acc(U, cur, col4, acc); cur = s; }
            acc.x += e * xv.x; acc.y += e * xv.y; acc.z += e * xv.z; acc.w += e * xv.w;
            if (lane == 0) { e_out[rb] = e; zloc += e; }
        }
    }

    if (cur >= 0) flush_acc(U, cur, col4, acc);

    // Z: wave -> block -> one atomic per block (kills the same-address convoy)
    zloc += __shfl_xor(zloc, 32);
    if (lane == 0) zred[wid] = zloc;
    __syncthreads();
    if (threadIdx.x == 0)
        atomicAdd(Z, zred[0] + zred[1] + zred[2] + zred[3]);
}

__global__ __launch_bounds__(256) void nap_finalize(
    const float* __restrict__ U, const float* __restrict__ Z,
    float* __restrict__ pooled, float* __restrict__ alpha,
    int gc, int n)
{
    const float inv = 1.0f / (*Z);
    const int tid = blockIdx.x * blockDim.x + threadIdx.x;
    const int stride = gridDim.x * blockDim.x;
    const int gc4 = gc >> 2;
    const int n4 = n >> 2;
    for (int k = tid; k < gc4; k += stride) {
        float4 u = ((const float4*)U)[k];
        u.x *= inv; u.y *= inv; u.z *= inv; u.w *= inv;
        ((float4*)pooled)[k] = u;
    }
    for (int k = tid; k < n4; k += stride) {
        float4 e = ((const float4*)alpha)[k];
        e.x *= inv; e.y *= inv; e.z *= inv; e.w *= inv;
        ((float4*)alpha)[k] = e;
    }
    for (int k = gc4 * 4 + tid; k < gc; k += stride) pooled[k] = U[k] * inv;
    for (int k = n4 * 4 + tid; k < n; k += stride) alpha[k] = alpha[k] * inv;
}

extern "C" void kernel_launch(void* const* d_in, const int* in_sizes, int n_in,
                              void* d_out, int out_size, void* d_ws, size_t ws_size,
                              hipStream_t stream) {
    const float* x     = (const float*)d_in[0];
    const float* W     = (const float*)d_in[1];
    const float* b     = (const float*)d_in[2];
    const int*   batch = (const int*)d_in[3];
    const int N = in_sizes[3];

    float* U = (float*)d_ws;                  // [G_SEGS * C_CH] unnormalized sums
    float* Z = U + (size_t)G_SEGS * C_CH;     // [1] global sum of exp
    float* pooled = (float*)d_out;                    // [G_SEGS * C_CH]
    float* alpha  = pooled + (size_t)G_SEGS * C_CH;   // [N]

    hipMemsetAsync(d_ws, 0, ((size_t)G_SEGS * C_CH + 1) * sizeof(float), stream);

    nap_main<<<2048, 256, 0, stream>>>(x, W, b, batch, U, Z, alpha, N);
    nap_finalize<<<512, 256, 0, stream>>>(U, Z, pooled, alpha, G_SEGS * C_CH, N);
}

// Round 3
// 674.991 us; speedup vs baseline: 1.1292x; 1.0002x over previous
//
#include <hip/hip_runtime.h>

#define C_CH 128
#define G_SEGS 1024

// Flush a lane's per-segment float4 accumulator into U[seg][col4*4..+3].
__device__ __forceinline__ void flush_acc(float* __restrict__ U, int seg, int col4,
                                          float4& acc) {
    float* dst = U + (size_t)seg * C_CH + col4 * 4;
    atomicAdd(dst + 0, acc.x);
    atomicAdd(dst + 1, acc.y);
    atomicAdd(dst + 2, acc.z);
    atomicAdd(dst + 3, acc.w);
    acc = make_float4(0.f, 0.f, 0.f, 0.f);
}

// 8 rows per wave group, software-pipelined: group g+1's 4×1KB loads and
// batch scalars are issued (branchlessly, clamped address) BEFORE group g is
// processed, so every wave keeps 4KB in flight through the compute phase.
// Row mapping: float4 f = i*64+lane -> row rb+2i+(lane>>5), col4 = lane&31.
__global__ __launch_bounds__(256) void nap_main(
    const float* __restrict__ x, const float* __restrict__ W,
    const float* __restrict__ b, const int* __restrict__ batch,
    float* __restrict__ U, float* __restrict__ Z,
    float* __restrict__ e_out, int N)
{
    __shared__ float zred[4];
    const int lane = threadIdx.x & 63;
    const int wid  = threadIdx.x >> 6;
    const int wave = (blockIdx.x * blockDim.x + threadIdx.x) >> 6;
    const int nwaves = (gridDim.x * blockDim.x) >> 6;
    int chunk = (N + nwaves - 1) / nwaves;
    chunk = (chunk + 7) & ~7;                 // multiple of 8 rows per wave
    const int row0 = wave * chunk;
    const int row1 = min(N, row0 + chunk);

    const int col4 = lane & 31;               // which float4 of a row this lane owns
    const int h    = lane >> 5;               // row-parity half
    const float4 w4 = ((const float4*)W)[col4];
    const float bv = b[0];
    const float4* x4 = (const float4*)x;

    float4 acc = make_float4(0.f, 0.f, 0.f, 0.f);
    float zloc = 0.f;
    int cur = -1;

    const int ngroups = (row1 > row0) ? ((row1 - row0) >> 3) : 0;

    float4 a0, a1, a2, a3;
    int bfirst = 0, blast = 0;
    if (ngroups > 0) {
        const float4* p = x4 + (size_t)row0 * (C_CH / 4);
        a0 = p[lane]; a1 = p[64 + lane]; a2 = p[128 + lane]; a3 = p[192 + lane];
        const int r0u = __builtin_amdgcn_readfirstlane(row0);
        bfirst = batch[r0u];
        blast  = batch[r0u + 7];
    }

    for (int g = 0; g < ngroups; ++g) {
        const int rb  = row0 + g * 8;
        // ---- prefetch next group (clamped: last iteration re-reads rb, L1-hot)
        const int rbn = (g + 1 < ngroups) ? rb + 8 : rb;
        const float4* pn = x4 + (size_t)rbn * (C_CH / 4);
        const float4 n0 = pn[lane];
        const float4 n1 = pn[64  + lane];
        const float4 n2 = pn[128 + lane];
        const float4 n3 = pn[192 + lane];
        const int rbnu = __builtin_amdgcn_readfirstlane(rbn);
        const int nbf = batch[rbnu];
        const int nbl = batch[rbnu + 7];

        // ---- process current group
        float d0 = fmaf(a0.x, w4.x, fmaf(a0.y, w4.y, fmaf(a0.z, w4.z, a0.w * w4.w)));
        float d1 = fmaf(a1.x, w4.x, fmaf(a1.y, w4.y, fmaf(a1.z, w4.z, a1.w * w4.w)));
        float d2 = fmaf(a2.x, w4.x, fmaf(a2.y, w4.y, fmaf(a2.z, w4.z, a2.w * w4.w)));
        float d3 = fmaf(a3.x, w4.x, fmaf(a3.y, w4.y, fmaf(a3.z, w4.z, a3.w * w4.w)));
        #pragma unroll
        for (int m = 1; m <= 16; m <<= 1) {   // 4 chains interleaved, halves only
            d0 += __shfl_xor(d0, m);
            d1 += __shfl_xor(d1, m);
            d2 += __shfl_xor(d2, m);
            d3 += __shfl_xor(d3, m);
        }
        const float e0 = __expf(d0 + bv);
        const float e1 = __expf(d1 + bv);
        const float e2 = __expf(d2 + bv);
        const float e3 = __expf(d3 + bv);

        if (bfirst == blast) {                // uniform fast path: one segment
            if (bfirst != cur) {
                if (cur >= 0) flush_acc(U, cur, col4, acc);
                cur = bfirst;
            }
            acc.x += e0 * a0.x + e1 * a1.x + e2 * a2.x + e3 * a3.x;
            acc.y += e0 * a0.y + e1 * a1.y + e2 * a2.y + e3 * a3.y;
            acc.z += e0 * a0.z + e1 * a1.z + e2 * a2.z + e3 * a3.z;
            acc.w += e0 * a0.w + e1 * a1.w + e2 * a2.w + e3 * a3.w;
        } else {                              // rare: boundary inside the group
            const int r  = rb + h;            // this half's rows: r, r+2, r+4, r+6
            const int s0 = batch[r];
            const int s1 = batch[r + 2];
            const int s2 = batch[r + 4];
            const int s3 = batch[r + 6];
            if (s0 != cur) { if (cur >= 0) flush_acc(U, cur, col4, acc); cur = s0; }
            acc.x += e0 * a0.x; acc.y += e0 * a0.y; acc.z += e0 * a0.z; acc.w += e0 * a0.w;
            if (s1 != cur) { flush_acc(U, cur, col4, acc); cur = s1; }
            acc.x += e1 * a1.x; acc.y += e1 * a1.y; acc.z += e1 * a1.z; acc.w += e1 * a1.w;
            if (s2 != cur) { flush_acc(U, cur, col4, acc); cur = s2; }
            acc.x += e2 * a2.x; acc.y += e2 * a2.y; acc.z += e2 * a2.z; acc.w += e2 * a2.w;
            if (s3 != cur) { flush_acc(U, cur, col4, acc); cur = s3; }
            acc.x += e3 * a3.x; acc.y += e3 * a3.y; acc.z += e3 * a3.z; acc.w += e3 * a3.w;
        }

        // alpha (unnormalized exp) store: pack 8 rows into two float4 stores
        const float p0 = __shfl_xor(e0, 32);
        const float p1 = __shfl_xor(e1, 32);
        const float p2 = __shfl_xor(e2, 32);
        const float p3 = __shfl_xor(e3, 32);
        if (lane == 0) {
            ((float4*)(e_out + rb))[0] = make_float4(e0, p0, e1, p1);
            zloc += e0 + e1 + e2 + e3;
        } else if (lane == 32) {
            ((float4*)(e_out + rb))[1] = make_float4(p2, e2, p3, e3);
            zloc += e0 + e1 + e2 + e3;
        }

        // ---- rotate prefetched registers in
        a0 = n0; a1 = n1; a2 = n2; a3 = n3;
        bfirst = nbf; blast = nbl;
    }

    // generic scalar tail (never runs for N % 8 == 0, kept for safety)
    for (int rb = row0 + ngroups * 8; rb < row1; ++rb) {
        const float4 xv = x4[(size_t)rb * (C_CH / 4) + col4];
        float d = fmaf(xv.x, w4.x, fmaf(xv.y, w4.y, fmaf(xv.z, w4.z, xv.w * w4.w)));
        #pragma unroll
        for (int m = 1; m <= 16; m <<= 1) d += __shfl_xor(d, m);
        const float e = __expf(d + bv);
        const int s = batch[rb];
        if (h == 0) {
            if (s != cur) { if (cur >= 0) flush_acc(U, cur, col4, acc); cur = s; }
            acc.x += e * xv.x; acc.y += e * xv.y; acc.z += e * xv.z; acc.w += e * xv.w;
            if (lane == 0) { e_out[rb] = e; zloc += e; }
        }
    }

    if (cur >= 0) flush_acc(U, cur, col4, acc);

    // Z: wave -> block -> one atomic per block
    zloc += __shfl_xor(zloc, 32);
    if (lane == 0) zred[wid] = zloc;
    __syncthreads();
    if (threadIdx.x == 0)
        atomicAdd(Z, zred[0] + zred[1] + zred[2] + zred[3]);
}

__global__ __launch_bounds__(256) void nap_finalize(
    const float* __restrict__ U, const float* __restrict__ Z,
    float* __restrict__ pooled, float* __restrict__ alpha,
    int gc, int n)
{
    const float inv = 1.0f / (*Z);
    const int tid = blockIdx.x * blockDim.x + threadIdx.x;
    const int stride = gridDim.x * blockDim.x;
    const int gc4 = gc >> 2;
    const int n4 = n >> 2;
    for (int k = tid; k < gc4; k += stride) {
        float4 u = ((const float4*)U)[k];
        u.x *= inv; u.y *= inv; u.z *= inv; u.w *= inv;
        ((float4*)pooled)[k] = u;
    }
    for (int k = tid; k < n4; k += stride) {
        float4 e = ((const float4*)alpha)[k];
        e.x *= inv; e.y *= inv; e.z *= inv; e.w *= inv;
        ((float4*)alpha)[k] = e;
    }
    for (int k = gc4 * 4 + tid; k < gc; k += stride) pooled[k] = U[k] * inv;
    for (int k = n4 * 4 + tid; k < n; k += stride) alpha[k] = alpha[k] * inv;
}

extern "C" void kernel_launch(void* const* d_in, const int* in_sizes, int n_in,
                              void* d_out, int out_size, void* d_ws, size_t ws_size,
                              hipStream_t stream) {
    const float* x     = (const float*)d_in[0];
    const float* W     = (const float*)d_in[1];
    const float* b     = (const float*)d_in[2];
    const int*   batch = (const int*)d_in[3];
    const int N = in_sizes[3];

    float* U = (float*)d_ws;                  // [G_SEGS * C_CH] unnormalized sums
    float* Z = U + (size_t)G_SEGS * C_CH;     // [1] global sum of exp
    float* pooled = (float*)d_out;                    // [G_SEGS * C_CH]
    float* alpha  = pooled + (size_t)G_SEGS * C_CH;   // [N]

    hipMemsetAsync(d_ws, 0, ((size_t)G_SEGS * C_CH + 1) * sizeof(float), stream);

    nap_main<<<2048, 256, 0, stream>>>(x, W, b, batch, U, Z, alpha, N);
    nap_finalize<<<512, 256, 0, stream>>>(U, Z, pooled, alpha, G_SEGS * C_CH, N);
}

// Round 4
// 648.228 us; speedup vs baseline: 1.1758x; 1.0413x over previous
//
#include <hip/hip_runtime.h>

#define C_CH 128
#define G_SEGS 1024

typedef float v4f __attribute__((ext_vector_type(4)));

__device__ __forceinline__ v4f fma4(v4f a, float s, v4f c) {
    c.x = fmaf(a.x, s, c.x);
    c.y = fmaf(a.y, s, c.y);
    c.z = fmaf(a.z, s, c.z);
    c.w = fmaf(a.w, s, c.w);
    return c;
}

__device__ __forceinline__ void flush_acc(float* __restrict__ U, int seg, int col4,
                                          v4f& acc) {
    float* dst = U + (size_t)seg * C_CH + col4 * 4;
    atomicAdd(dst + 0, acc.x);
    atomicAdd(dst + 1, acc.y);
    atomicAdd(dst + 2, acc.z);
    atomicAdd(dst + 3, acc.w);
    acc = (v4f){0.f, 0.f, 0.f, 0.f};
}

// 16 rows per wave iteration, 8 nontemporal 1KB loads (8KB contiguous).
// float4 f = i*64+lane -> row rb+2i+(lane>>5), col4 = lane&31; chain i holds
// rows rb+2i (half 0) and rb+2i+1 (half 1). Sorted batch => wave-uniform
// fast path via batch[rb]==batch[rb+15]. Grid sized for guaranteed single
// dispatch pass (1536 blocks), no register rotation (R3 showed prefetch is
// worthless -- MLP across 24 resident waves/CU already covers HBM latency).
__global__ __launch_bounds__(256) void nap_main(
    const float* __restrict__ x, const float* __restrict__ W,
    const float* __restrict__ b, const int* __restrict__ batch,
    float* __restrict__ U, float* __restrict__ Z,
    float* __restrict__ e_out, int N)
{
    __shared__ float zred[4];
    const int lane = threadIdx.x & 63;
    const int wid  = threadIdx.x >> 6;
    const int wave = (blockIdx.x * blockDim.x + threadIdx.x) >> 6;
    const int nwaves = (gridDim.x * blockDim.x) >> 6;
    int chunk = (N + nwaves - 1) / nwaves;
    chunk = (chunk + 15) & ~15;               // multiple of 16 rows per wave
    const int row0 = min(N, wave * chunk);
    const int row1 = min(N, row0 + chunk);

    const int col4 = lane & 31;               // which float4 of a row this lane owns
    const int h    = lane >> 5;               // row-parity half
    const v4f w4 = ((const v4f*)W)[col4];
    const float bv = b[0];
    const v4f* x4 = (const v4f*)x;

    v4f acc = {0.f, 0.f, 0.f, 0.f};
    float zloc = 0.f;
    int cur = -1;

    const int ng = (row1 - row0) >> 4;        // 16-row groups

    for (int g = 0; g < ng; ++g) {
        const int rb = row0 + g * 16;
        const v4f* p = x4 + (size_t)rb * (C_CH / 4);
        const v4f a0 = __builtin_nontemporal_load(p + lane);         // rows 0,1
        const v4f a1 = __builtin_nontemporal_load(p + 64  + lane);   // rows 2,3
        const v4f a2 = __builtin_nontemporal_load(p + 128 + lane);   // rows 4,5
        const v4f a3 = __builtin_nontemporal_load(p + 192 + lane);   // rows 6,7
        const v4f b0 = __builtin_nontemporal_load(p + 256 + lane);   // rows 8,9
        const v4f b1 = __builtin_nontemporal_load(p + 320 + lane);   // rows 10,11
        const v4f b2 = __builtin_nontemporal_load(p + 384 + lane);   // rows 12,13
        const v4f b3 = __builtin_nontemporal_load(p + 448 + lane);   // rows 14,15
        const int rbu = __builtin_amdgcn_readfirstlane(rb);
        const int bf = batch[rbu];            // wave-uniform -> s_load
        const int bl = batch[rbu + 15];

        float d0 = fmaf(a0.x, w4.x, fmaf(a0.y, w4.y, fmaf(a0.z, w4.z, a0.w * w4.w)));
        float d1 = fmaf(a1.x, w4.x, fmaf(a1.y, w4.y, fmaf(a1.z, w4.z, a1.w * w4.w)));
        float d2 = fmaf(a2.x, w4.x, fmaf(a2.y, w4.y, fmaf(a2.z, w4.z, a2.w * w4.w)));
        float d3 = fmaf(a3.x, w4.x, fmaf(a3.y, w4.y, fmaf(a3.z, w4.z, a3.w * w4.w)));
        float d4 = fmaf(b0.x, w4.x, fmaf(b0.y, w4.y, fmaf(b0.z, w4.z, b0.w * w4.w)));
        float d5 = fmaf(b1.x, w4.x, fmaf(b1.y, w4.y, fmaf(b1.z, w4.z, b1.w * w4.w)));
        float d6 = fmaf(b2.x, w4.x, fmaf(b2.y, w4.y, fmaf(b2.z, w4.z, b2.w * w4.w)));
        float d7 = fmaf(b3.x, w4.x, fmaf(b3.y, w4.y, fmaf(b3.z, w4.z, b3.w * w4.w)));
        #pragma unroll
        for (int m = 1; m <= 16; m <<= 1) {   // 8 chains interleaved, halves only
            d0 += __shfl_xor(d0, m);
            d1 += __shfl_xor(d1, m);
            d2 += __shfl_xor(d2, m);
            d3 += __shfl_xor(d3, m);
            d4 += __shfl_xor(d4, m);
            d5 += __shfl_xor(d5, m);
            d6 += __shfl_xor(d6, m);
            d7 += __shfl_xor(d7, m);
        }
        const float e0 = __expf(d0 + bv);
        const float e1 = __expf(d1 + bv);
        const float e2 = __expf(d2 + bv);
        const float e3 = __expf(d3 + bv);
        const float e4 = __expf(d4 + bv);
        const float e5 = __expf(d5 + bv);
        const float e6 = __expf(d6 + bv);
        const float e7 = __expf(d7 + bv);

        if (bf == bl) {                       // uniform fast path: one segment
            if (bf != cur) {
                if (cur >= 0) flush_acc(U, cur, col4, acc);
                cur = bf;
            }
            acc.x += e0*a0.x + e1*a1.x + e2*a2.x + e3*a3.x
                   + e4*b0.x + e5*b1.x + e6*b2.x + e7*b3.x;
            acc.y += e0*a0.y + e1*a1.y + e2*a2.y + e3*a3.y
                   + e4*b0.y + e5*b1.y + e6*b2.y + e7*b3.y;
            acc.z += e0*a0.z + e1*a1.z + e2*a2.z + e3*a3.z
                   + e4*b0.z + e5*b1.z + e6*b2.z + e7*b3.z;
            acc.w += e0*a0.w + e1*a1.w + e2*a2.w + e3*a3.w
                   + e4*b0.w + e5*b1.w + e6*b2.w + e7*b3.w;
        } else {                              // rare: boundary inside the group
            const int r = rb + h;             // this half's rows: r, r+2, ..., r+14
            const int s0 = batch[r];
            const int s1 = batch[r + 2];
            const int s2 = batch[r + 4];
            const int s3 = batch[r + 6];
            const int s4 = batch[r + 8];
            const int s5 = batch[r + 10];
            const int s6 = batch[r + 12];
            const int s7 = batch[r + 14];
            if (s0 != cur) { if (cur >= 0) flush_acc(U, cur, col4, acc); cur = s0; }
            acc = fma4(a0, e0, acc);
            if (s1 != cur) { flush_acc(U, cur, col4, acc); cur = s1; }
            acc = fma4(a1, e1, acc);
            if (s2 != cur) { flush_acc(U, cur, col4, acc); cur = s2; }
            acc = fma4(a2, e2, acc);
            if (s3 != cur) { flush_acc(U, cur, col4, acc); cur = s3; }
            acc = fma4(a3, e3, acc);
            if (s4 != cur) { flush_acc(U, cur, col4, acc); cur = s4; }
            acc = fma4(b0, e4, acc);
            if (s5 != cur) { flush_acc(U, cur, col4, acc); cur = s5; }
            acc = fma4(b1, e5, acc);
            if (s6 != cur) { flush_acc(U, cur, col4, acc); cur = s6; }
            acc = fma4(b2, e6, acc);
            if (s7 != cur) { flush_acc(U, cur, col4, acc); cur = s7; }
            acc = fma4(b3, e7, acc);
        }

        // alpha (unnormalized exp): 16 rows -> four float4 nt stores (2 lanes)
        const float p0 = __shfl_xor(e0, 32);
        const float p1 = __shfl_xor(e1, 32);
        const float p2 = __shfl_xor(e2, 32);
        const float p3 = __shfl_xor(e3, 32);
        const float p4 = __shfl_xor(e4, 32);
        const float p5 = __shfl_xor(e5, 32);
        const float p6 = __shfl_xor(e6, 32);
        const float p7 = __shfl_xor(e7, 32);
        if (lane == 0) {
            v4f u0 = {e0, p0, e1, p1};        // rows 0..3
            v4f u1 = {e4, p4, e5, p5};        // rows 8..11
            __builtin_nontemporal_store(u0, (v4f*)(e_out + rb));
            __builtin_nontemporal_store(u1, (v4f*)(e_out + rb + 8));
            zloc += e0 + e1 + e2 + e3 + e4 + e5 + e6 + e7;   // even rows
        } else if (lane == 32) {
            v4f u0 = {p2, e2, p3, e3};        // rows 4..7
            v4f u1 = {p6, e6, p7, e7};        // rows 12..15
            __builtin_nontemporal_store(u0, (v4f*)(e_out + rb + 4));
            __builtin_nontemporal_store(u1, (v4f*)(e_out + rb + 12));
            zloc += e0 + e1 + e2 + e3 + e4 + e5 + e6 + e7;   // odd rows
        }
    }

    // generic scalar tail (unused when chunk divides cleanly; kept for safety)
    for (int rb = row0 + ng * 16; rb < row1; ++rb) {
        const v4f xv = x4[(size_t)rb * (C_CH / 4) + col4];
        float d = fmaf(xv.x, w4.x, fmaf(xv.y, w4.y, fmaf(xv.z, w4.z, xv.w * w4.w)));
        #pragma unroll
        for (int m = 1; m <= 16; m <<= 1) d += __shfl_xor(d, m);
        const float e = __expf(d + bv);
        const int s = batch[rb];
        if (h == 0) {
            if (s != cur) { if (cur >= 0) flush_acc(U, cur, col4, acc); cur = s; }
            acc = fma4(xv, e, acc);
            if (lane == 0) { e_out[rb] = e; zloc += e; }
        }
    }

    if (cur >= 0) flush_acc(U, cur, col4, acc);

    // Z: wave -> block -> one atomic per block
    zloc += __shfl_xor(zloc, 32);
    if (lane == 0) zred[wid] = zloc;
    __syncthreads();
    if (threadIdx.x == 0)
        atomicAdd(Z, zred[0] + zred[1] + zred[2] + zred[3]);
}

__global__ __launch_bounds__(256) void nap_finalize(
    const float* __restrict__ U, const float* __restrict__ Z,
    float* __restrict__ pooled, float* __restrict__ alpha,
    int gc, int n)
{
    const float inv = 1.0f / (*Z);
    const int tid = blockIdx.x * blockDim.x + threadIdx.x;
    const int stride = gridDim.x * blockDim.x;
    const int gc4 = gc >> 2;
    const int n4 = n >> 2;
    for (int k = tid; k < gc4; k += stride) {
        v4f u = ((const v4f*)U)[k];
        u.x *= inv; u.y *= inv; u.z *= inv; u.w *= inv;
        __builtin_nontemporal_store(u, (v4f*)pooled + k);
    }
    for (int k = tid; k < n4; k += stride) {
        v4f e = ((const v4f*)alpha)[k];
        e.x *= inv; e.y *= inv; e.z *= inv; e.w *= inv;
        __builtin_nontemporal_store(e, (v4f*)alpha + k);
    }
    for (int k = gc4 * 4 + tid; k < gc; k += stride) pooled[k] = U[k] * inv;
    for (int k = n4 * 4 + tid; k < n; k += stride) alpha[k] = alpha[k] * inv;
}

extern "C" void kernel_launch(void* const* d_in, const int* in_sizes, int n_in,
                              void* d_out, int out_size, void* d_ws, size_t ws_size,
                              hipStream_t stream) {
    const float* x     = (const float*)d_in[0];
    const float* W     = (const float*)d_in[1];
    const float* b     = (const float*)d_in[2];
    const int*   batch = (const int*)d_in[3];
    const int N = in_sizes[3];

    float* U = (float*)d_ws;                  // [G_SEGS * C_CH] unnormalized sums
    float* Z = U + (size_t)G_SEGS * C_CH;     // [1] global sum of exp
    float* pooled = (float*)d_out;                    // [G_SEGS * C_CH]
    float* alpha  = pooled + (size_t)G_SEGS * C_CH;   // [N]

    hipMemsetAsync(d_ws, 0, ((size_t)G_SEGS * C_CH + 1) * sizeof(float), stream);

    // 1536 blocks = 6144 waves: co-resident in one dispatch pass at >=6
    // waves/SIMD, so every wave starts at t=0 (no dispatch tail).
    nap_main<<<1536, 256, 0, stream>>>(x, W, b, batch, U, Z, alpha, N);
    nap_finalize<<<512, 256, 0, stream>>>(U, Z, pooled, alpha, G_SEGS * C_CH, N);
}